// Round 15
// baseline (1016.127 us; speedup 1.0000x reference)
//
#include <hip/hip_runtime.h>

// GRU: B=256, T=2048, I=2, H=128. One workgroup per batch element.
// R15 = R13 (best: 922 us) + ONE change: x[t] comes from GLOBAL via a
// vmcnt prefetch (loaded at loop top, consumed next iteration -> ~1000 cyc
// of slack, wait is free) instead of an LDS read. This removes 4 wave-
// instrs/step from the contended post-barrier lgkmcnt stream (16 h-reads
// across 4 waves serialize on the LDS pipe) and decouples the x-wait from
// the critical drain. x staging (16 KB LDS) deleted.
// R14's bundled reorder/pointer-swap regressed (922 -> 942): reverted.
// R13 structure frozen: NT=256 (4 waves, 1/SIMD), thread (q=tid&3,
// jp=tid>>2) owns gates {r,z,n} x units {jp, 64+jp}, cols [32q,32q+32);
// fp16 h in LDS (fp32 recurrence on producers), prescaled fp16 weights +
// v_dot2_f32_f16; xp/bhn folded into acc init (x1/4); non-volatile
// single-instr v_add_f32_dpp quad butterfly (acc-major interleave);
// exp2/rcp gates; one barrier/step; 40-half slice stride (conflict-free).
// Falsified (do not revisit): 16-col/8-lane-reduce (R4/R6/R10); VGPR
// residency forcing (R3/R8); volatile DPP fences (R4/R6); gate-major dot
// split (R14).

#define BB 256
#define TT 2048
#define HH 128
#define NT 256
#define HHALFS 160   // per buffer: 4 slices x 40 halfs (32 data + 8 pad)

typedef _Float16 v2h __attribute__((ext_vector_type(2)));
typedef _Float16 v8h __attribute__((ext_vector_type(8)));

// x += dpp(x) in one v_add_f32_dpp; s_nop 1 covers the VALU->DPP hazard.
// Non-volatile: schedulable.
#define DPP_ADD_Q(x, QPSTR) do { float _d;                                   \
    asm("s_nop 1\n\t"                                                        \
        "v_add_f32_dpp %0, %1, %1 " QPSTR " row_mask:0xf bank_mask:0xf"      \
        : "=v"(_d) : "v"(x));                                                \
    (x) = _d; } while (0)

__global__ __launch_bounds__(NT, 1) void gru_seq_kernel(
    const float* __restrict__ x,        // [B, T, 2]
    const int*   __restrict__ lengths,  // [B]
    const float* __restrict__ W_ih,     // [384, 2]
    const float* __restrict__ W_hh,     // [384, 128]
    const float* __restrict__ b_ih,     // [384]
    const float* __restrict__ b_hh,     // [384]
    const float* __restrict__ head_w,   // [128]
    const float* __restrict__ head_b,   // [1]
    float* __restrict__ out)            // [B]
{
    __shared__ __align__(16) _Float16 h_lds[2][HHALFS];      // 640 B
    __shared__ float red[HH];

    const int tid = threadIdx.x;
    const int q  = tid & 3;          // 32-col slice
    const int jp = tid >> 2;         // unit-pair index 0..63
    const int b  = blockIdx.x;
    const int len = lengths[b];

    const float S_RZ = -1.4426950408889634f;   // -log2(e)
    const float S_N  =  2.8853900817779268f;   //  2*log2(e)

    // --- weights: 6 rows (g x p) x 32-col slice q, prescaled fp16 ---
    v2h wv[6][16];
    #pragma unroll
    for (int g = 0; g < 3; ++g) {
        const float s = (g == 2) ? S_N : S_RZ;
        #pragma unroll
        for (int p = 0; p < 2; ++p) {
            const float4* Wp = (const float4*)(W_hh + (size_t)(g * HH + 64 * p + jp) * HH + 32 * q);
            #pragma unroll
            for (int i = 0; i < 8; ++i) {
                const float4 w4 = Wp[i];
                wv[g * 2 + p][2 * i]     = (v2h){(_Float16)(s * w4.x), (_Float16)(s * w4.y)};
                wv[g * 2 + p][2 * i + 1] = (v2h){(_Float16)(s * w4.z), (_Float16)(s * w4.w)};
            }
        }
    }

    // --- all-lane init constants (x 1/4: quad butterfly sums 4 replicas) ---
    float wir0[2], wir1[2], br4[2], wiz0[2], wiz1[2], bz4[2], bhn4[2];
    #pragma unroll
    for (int p = 0; p < 2; ++p) {
        const int u = 64 * p + jp;
        const float s4 = S_RZ * 0.25f;
        wir0[p] = s4 * W_ih[u * 2];        wir1[p] = s4 * W_ih[u * 2 + 1];
        br4[p]  = s4 * (b_ih[u] + b_hh[u]);
        wiz0[p] = s4 * W_ih[(HH + u) * 2]; wiz1[p] = s4 * W_ih[(HH + u) * 2 + 1];
        bz4[p]  = s4 * (b_ih[HH + u] + b_hh[HH + u]);
        bhn4[p] = (S_N * 0.25f) * b_hh[2 * HH + u];
    }

    // --- per-lane consumer unit: uSel = 64*(q&1) + jp ---
    const int pSel = q & 1;
    const int uSel = 64 * pSel + jp;
    const float win0 = S_N * W_ih[(2 * HH + uSel) * 2];
    const float win1 = S_N * W_ih[(2 * HH + uSel) * 2 + 1];
    const float bn   = S_N * b_ih[2 * HH + uSel];
    const float hw   = head_w[uSel];

    // zero both h buffers
    for (int i = tid; i < 2 * HHALFS; i += NT) ((_Float16*)h_lds)[i] = (_Float16)0.f;

    __syncthreads();

    float h_reg = 0.0f;   // fp32 h[uSel]; live on lanes q<2
    int buf = 0;
    const float2* xg2 = (const float2*)(x + (size_t)b * TT * 2);
    float2 xt = xg2[0];   // x for step 0 (global; L1/L2 broadcast)

    for (int t = 0; t < len; ++t) {
        // h slice q: 4 x ds_read_b128 of fp16 (quad-broadcast, conflict-free)
        const v8h* hb = (const v8h*)(&h_lds[buf][40 * q]);
        v8h hv[4];
        #pragma unroll
        for (int i = 0; i < 4; ++i) hv[i] = hb[i];

        // global x prefetch (vmcnt; consumed next iteration -> wait free)
        const int tn = (t + 1 < TT) ? t + 1 : TT - 1;
        const float2 xt_next = xg2[tn];

        v2h h2[16];
        #pragma unroll
        for (int i = 0; i < 4; ++i) {
            h2[4*i+0] = __builtin_shufflevector(hv[i], hv[i], 0, 1);
            h2[4*i+1] = __builtin_shufflevector(hv[i], hv[i], 2, 3);
            h2[4*i+2] = __builtin_shufflevector(hv[i], hv[i], 4, 5);
            h2[4*i+3] = __builtin_shufflevector(hv[i], hv[i], 6, 7);
        }

        // acc inits: xp/4 (r,z) and bhn/4 (n), per unit p
        float aR[2], aZ[2], aN[2];
        #pragma unroll
        for (int p = 0; p < 2; ++p) {
            aR[p] = fmaf(wir0[p], xt.x, fmaf(wir1[p], xt.y, br4[p]));
            aZ[p] = fmaf(wiz0[p], xt.x, fmaf(wiz1[p], xt.y, bz4[p]));
            aN[p] = bhn4[p];
        }

        // 6 dots x 16 dot2 (fp32 accumulate), 6-way ILP
        #pragma unroll
        for (int i = 0; i < 16; ++i) {
            aR[0] = __builtin_amdgcn_fdot2(wv[0][i], h2[i], aR[0], false);
            aR[1] = __builtin_amdgcn_fdot2(wv[1][i], h2[i], aR[1], false);
            aZ[0] = __builtin_amdgcn_fdot2(wv[2][i], h2[i], aZ[0], false);
            aZ[1] = __builtin_amdgcn_fdot2(wv[3][i], h2[i], aZ[1], false);
            aN[0] = __builtin_amdgcn_fdot2(wv[4][i], h2[i], aN[0], false);
            aN[1] = __builtin_amdgcn_fdot2(wv[5][i], h2[i], aN[1], false);
        }

        // quad butterfly, acc-major interleave (non-volatile, schedulable)
        DPP_ADD_Q(aR[0], "quad_perm:[1,0,3,2]");
        DPP_ADD_Q(aR[1], "quad_perm:[1,0,3,2]");
        DPP_ADD_Q(aZ[0], "quad_perm:[1,0,3,2]");
        DPP_ADD_Q(aZ[1], "quad_perm:[1,0,3,2]");
        DPP_ADD_Q(aN[0], "quad_perm:[1,0,3,2]");
        DPP_ADD_Q(aN[1], "quad_perm:[1,0,3,2]");
        DPP_ADD_Q(aR[0], "quad_perm:[2,3,0,1]");
        DPP_ADD_Q(aR[1], "quad_perm:[2,3,0,1]");
        DPP_ADD_Q(aZ[0], "quad_perm:[2,3,0,1]");
        DPP_ADD_Q(aZ[1], "quad_perm:[2,3,0,1]");
        DPP_ADD_Q(aN[0], "quad_perm:[2,3,0,1]");
        DPP_ADD_Q(aN[1], "quad_perm:[2,3,0,1]");

        // pick this lane's unit (pSel = q&1); lanes q>=2 compute a dup
        const float ar = pSel ? aR[1] : aR[0];
        const float az = pSel ? aZ[1] : aZ[0];
        const float an = pSel ? aN[1] : aN[0];

        // gate chain (unmasked; ar/az/an include xp and biases, prescaled)
        const float r = __builtin_amdgcn_rcpf(1.f + __builtin_amdgcn_exp2f(ar));
        const float z = __builtin_amdgcn_rcpf(1.f + __builtin_amdgcn_exp2f(az));
        const float xn = fmaf(win0, xt.x, fmaf(win1, xt.y, bn));
        const float u = __builtin_amdgcn_exp2f(fmaf(r, an, xn));
        const float n = fmaf(-2.f, __builtin_amdgcn_rcpf(1.f + u), 1.f);
        const float h_new = n + z * (h_reg - n);
        if (q < 2) {
            h_reg = h_new;
            h_lds[buf ^ 1][40 * (uSel >> 5) + (uSel & 31)] = (_Float16)h_new;
        }
        __syncthreads();
        buf ^= 1;
        xt = xt_next;
    }

    // --- head: out[b] = dot(h, head_w) + head_b ---
    if (q < 2) red[uSel] = h_reg * hw;
    __syncthreads();
    if (tid < 64) {
        float v = red[tid] + red[tid + 64];
        #pragma unroll
        for (int off = 32; off > 0; off >>= 1) v += __shfl_xor(v, off, 64);
        if (tid == 0) out[b] = v + head_b[0];
    }
}

extern "C" void kernel_launch(void* const* d_in, const int* in_sizes, int n_in,
                              void* d_out, int out_size, void* d_ws, size_t ws_size,
                              hipStream_t stream) {
    const float* x      = (const float*)d_in[0];
    const int*   len    = (const int*)  d_in[1];
    const float* W_ih   = (const float*)d_in[2];
    const float* W_hh   = (const float*)d_in[3];
    const float* b_ih   = (const float*)d_in[4];
    const float* b_hh   = (const float*)d_in[5];
    const float* head_w = (const float*)d_in[6];
    const float* head_b = (const float*)d_in[7];
    float* out = (float*)d_out;

    gru_seq_kernel<<<BB, NT, 0, stream>>>(x, len, W_ih, W_hh, b_ih, b_hh,
                                          head_w, head_b, out);
}

// Round 16
// 917.564 us; speedup vs baseline: 1.1074x; 1.1074x over previous
//
#include <hip/hip_runtime.h>

// GRU: B=256, T=2048, I=2, H=128. One workgroup per batch element.
// R16 = R13 VERBATIM (measured best: 922 us). R14 (schedule shaping, -2%)
// and R15 (global-x prefetch, -10%) both regressed; reverted.
// Structure: NT=256 (4 waves, 1/SIMD), thread (q=tid&3, jp=tid>>2) owns
// gates {r,z,n} x units {jp, 64+jp}, cols [32q,32q+32); fp16 h in LDS
// (fp32 recurrence on producers), prescaled fp16 weights + v_dot2_f32_f16;
// xp/bhn folded into acc init (x1/4); non-volatile single-instr
// v_add_f32_dpp quad butterfly (acc-major interleave); exp2/rcp gates;
// x staged in LDS with t+1 prefetch; one barrier/step; 40-half slice
// stride (conflict-free quad broadcast).
// Step accounting at 1050 cyc: ~310 VALU issue + ~190 LDS drain (16
// wave-reads, structural at 64 B/lane) + ~120 read latency + ~80 gate tail
// + ~100 barrier. All terms at measured minima for this design.
// Falsified (do not revisit): 16-col/8-lane-reduce (R4/R6/R10); VGPR
// residency forcing (R3/R8); volatile DPP fences (R4/R6); gate-major dot
// split + pointer swap (R14); per-step global x (R15); MFMA GEMV (1/16
// utilization, worked arithmetic); select-first butterfly (algebra).

#define BB 256
#define TT 2048
#define HH 128
#define NT 256
#define HHALFS 160   // per buffer: 4 slices x 40 halfs (32 data + 8 pad)

typedef _Float16 v2h __attribute__((ext_vector_type(2)));
typedef _Float16 v8h __attribute__((ext_vector_type(8)));

// x += dpp(x) in one v_add_f32_dpp; s_nop 1 covers the VALU->DPP hazard.
// Non-volatile: schedulable.
#define DPP_ADD_Q(x, QPSTR) do { float _d;                                   \
    asm("s_nop 1\n\t"                                                        \
        "v_add_f32_dpp %0, %1, %1 " QPSTR " row_mask:0xf bank_mask:0xf"      \
        : "=v"(_d) : "v"(x));                                                \
    (x) = _d; } while (0)

__global__ __launch_bounds__(NT, 1) void gru_seq_kernel(
    const float* __restrict__ x,        // [B, T, 2]
    const int*   __restrict__ lengths,  // [B]
    const float* __restrict__ W_ih,     // [384, 2]
    const float* __restrict__ W_hh,     // [384, 128]
    const float* __restrict__ b_ih,     // [384]
    const float* __restrict__ b_hh,     // [384]
    const float* __restrict__ head_w,   // [128]
    const float* __restrict__ head_b,   // [1]
    float* __restrict__ out)            // [B]
{
    __shared__ __align__(16) float x_lds[(TT + 1) * 2];      // 16 KB (+prefetch)
    __shared__ __align__(16) _Float16 h_lds[2][HHALFS];      // 640 B
    __shared__ float red[HH];

    const int tid = threadIdx.x;
    const int q  = tid & 3;          // 32-col slice
    const int jp = tid >> 2;         // unit-pair index 0..63
    const int b  = blockIdx.x;
    const int len = lengths[b];

    const float S_RZ = -1.4426950408889634f;   // -log2(e)
    const float S_N  =  2.8853900817779268f;   //  2*log2(e)

    // --- weights: 6 rows (g x p) x 32-col slice q, prescaled fp16 ---
    v2h wv[6][16];
    #pragma unroll
    for (int g = 0; g < 3; ++g) {
        const float s = (g == 2) ? S_N : S_RZ;
        #pragma unroll
        for (int p = 0; p < 2; ++p) {
            const float4* Wp = (const float4*)(W_hh + (size_t)(g * HH + 64 * p + jp) * HH + 32 * q);
            #pragma unroll
            for (int i = 0; i < 8; ++i) {
                const float4 w4 = Wp[i];
                wv[g * 2 + p][2 * i]     = (v2h){(_Float16)(s * w4.x), (_Float16)(s * w4.y)};
                wv[g * 2 + p][2 * i + 1] = (v2h){(_Float16)(s * w4.z), (_Float16)(s * w4.w)};
            }
        }
    }

    // --- all-lane init constants (x 1/4: quad butterfly sums 4 replicas) ---
    float wir0[2], wir1[2], br4[2], wiz0[2], wiz1[2], bz4[2], bhn4[2];
    #pragma unroll
    for (int p = 0; p < 2; ++p) {
        const int u = 64 * p + jp;
        const float s4 = S_RZ * 0.25f;
        wir0[p] = s4 * W_ih[u * 2];        wir1[p] = s4 * W_ih[u * 2 + 1];
        br4[p]  = s4 * (b_ih[u] + b_hh[u]);
        wiz0[p] = s4 * W_ih[(HH + u) * 2]; wiz1[p] = s4 * W_ih[(HH + u) * 2 + 1];
        bz4[p]  = s4 * (b_ih[HH + u] + b_hh[HH + u]);
        bhn4[p] = (S_N * 0.25f) * b_hh[2 * HH + u];
    }

    // --- per-lane consumer unit: uSel = 64*(q&1) + jp ---
    const int pSel = q & 1;
    const int uSel = 64 * pSel + jp;
    const float win0 = S_N * W_ih[(2 * HH + uSel) * 2];
    const float win1 = S_N * W_ih[(2 * HH + uSel) * 2 + 1];
    const float bn   = S_N * b_ih[2 * HH + uSel];
    const float hw   = head_w[uSel];

    // --- stage x[b] into LDS (float4, coalesced) ---
    {
        const float4* xb4 = (const float4*)(x + (size_t)b * TT * 2);
        float4* xl4 = (float4*)x_lds;
        #pragma unroll
        for (int i = tid; i < TT * 2 / 4; i += NT) xl4[i] = xb4[i];
    }
    if (tid == 0) { x_lds[TT * 2] = 0.f; x_lds[TT * 2 + 1] = 0.f; }
    for (int i = tid; i < 2 * HHALFS; i += NT) ((_Float16*)h_lds)[i] = (_Float16)0.f;

    __syncthreads();

    float h_reg = 0.0f;   // fp32 h[uSel]; live on lanes q<2
    int buf = 0;
    const float2* x2 = (const float2*)x_lds;
    float2 xt = x2[0];

    for (int t = 0; t < len; ++t) {
        // h slice q: 4 x ds_read_b128 of fp16 (quad-broadcast, conflict-free)
        const v8h* hb = (const v8h*)(&h_lds[buf][40 * q]);
        v8h hv[4];
        #pragma unroll
        for (int i = 0; i < 4; ++i) hv[i] = hb[i];

        const float2 xt_next = x2[t + 1];   // prefetch

        v2h h2[16];
        #pragma unroll
        for (int i = 0; i < 4; ++i) {
            h2[4*i+0] = __builtin_shufflevector(hv[i], hv[i], 0, 1);
            h2[4*i+1] = __builtin_shufflevector(hv[i], hv[i], 2, 3);
            h2[4*i+2] = __builtin_shufflevector(hv[i], hv[i], 4, 5);
            h2[4*i+3] = __builtin_shufflevector(hv[i], hv[i], 6, 7);
        }

        // acc inits: xp/4 (r,z) and bhn/4 (n), per unit p
        float aR[2], aZ[2], aN[2];
        #pragma unroll
        for (int p = 0; p < 2; ++p) {
            aR[p] = fmaf(wir0[p], xt.x, fmaf(wir1[p], xt.y, br4[p]));
            aZ[p] = fmaf(wiz0[p], xt.x, fmaf(wiz1[p], xt.y, bz4[p]));
            aN[p] = bhn4[p];
        }

        // 6 dots x 16 dot2 (fp32 accumulate), 6-way ILP
        #pragma unroll
        for (int i = 0; i < 16; ++i) {
            aR[0] = __builtin_amdgcn_fdot2(wv[0][i], h2[i], aR[0], false);
            aR[1] = __builtin_amdgcn_fdot2(wv[1][i], h2[i], aR[1], false);
            aZ[0] = __builtin_amdgcn_fdot2(wv[2][i], h2[i], aZ[0], false);
            aZ[1] = __builtin_amdgcn_fdot2(wv[3][i], h2[i], aZ[1], false);
            aN[0] = __builtin_amdgcn_fdot2(wv[4][i], h2[i], aN[0], false);
            aN[1] = __builtin_amdgcn_fdot2(wv[5][i], h2[i], aN[1], false);
        }

        // quad butterfly, acc-major interleave (non-volatile, schedulable)
        DPP_ADD_Q(aR[0], "quad_perm:[1,0,3,2]");
        DPP_ADD_Q(aR[1], "quad_perm:[1,0,3,2]");
        DPP_ADD_Q(aZ[0], "quad_perm:[1,0,3,2]");
        DPP_ADD_Q(aZ[1], "quad_perm:[1,0,3,2]");
        DPP_ADD_Q(aN[0], "quad_perm:[1,0,3,2]");
        DPP_ADD_Q(aN[1], "quad_perm:[1,0,3,2]");
        DPP_ADD_Q(aR[0], "quad_perm:[2,3,0,1]");
        DPP_ADD_Q(aR[1], "quad_perm:[2,3,0,1]");
        DPP_ADD_Q(aZ[0], "quad_perm:[2,3,0,1]");
        DPP_ADD_Q(aZ[1], "quad_perm:[2,3,0,1]");
        DPP_ADD_Q(aN[0], "quad_perm:[2,3,0,1]");
        DPP_ADD_Q(aN[1], "quad_perm:[2,3,0,1]");

        // pick this lane's unit (pSel = q&1); lanes q>=2 compute a dup
        const float ar = pSel ? aR[1] : aR[0];
        const float az = pSel ? aZ[1] : aZ[0];
        const float an = pSel ? aN[1] : aN[0];

        // gate chain (unmasked; ar/az/an include xp and biases, prescaled)
        const float r = __builtin_amdgcn_rcpf(1.f + __builtin_amdgcn_exp2f(ar));
        const float z = __builtin_amdgcn_rcpf(1.f + __builtin_amdgcn_exp2f(az));
        const float xn = fmaf(win0, xt.x, fmaf(win1, xt.y, bn));
        const float u = __builtin_amdgcn_exp2f(fmaf(r, an, xn));
        const float n = fmaf(-2.f, __builtin_amdgcn_rcpf(1.f + u), 1.f);
        const float h_new = n + z * (h_reg - n);
        if (q < 2) {
            h_reg = h_new;
            h_lds[buf ^ 1][40 * (uSel >> 5) + (uSel & 31)] = (_Float16)h_new;
        }
        __syncthreads();
        buf ^= 1;
        xt = xt_next;
    }

    // --- head: out[b] = dot(h, head_w) + head_b ---
    if (q < 2) red[uSel] = h_reg * hw;
    __syncthreads();
    if (tid < 64) {
        float v = red[tid] + red[tid + 64];
        #pragma unroll
        for (int off = 32; off > 0; off >>= 1) v += __shfl_xor(v, off, 64);
        if (tid == 0) out[b] = v + head_b[0];
    }
}

extern "C" void kernel_launch(void* const* d_in, const int* in_sizes, int n_in,
                              void* d_out, int out_size, void* d_ws, size_t ws_size,
                              hipStream_t stream) {
    const float* x      = (const float*)d_in[0];
    const int*   len    = (const int*)  d_in[1];
    const float* W_ih   = (const float*)d_in[2];
    const float* W_hh   = (const float*)d_in[3];
    const float* b_ih   = (const float*)d_in[4];
    const float* b_hh   = (const float*)d_in[5];
    const float* head_w = (const float*)d_in[6];
    const float* head_b = (const float*)d_in[7];
    float* out = (float*)d_out;

    gru_seq_kernel<<<BB, NT, 0, stream>>>(x, len, W_ih, W_hh, b_ih, b_hh,
                                          head_w, head_b, out);
}